// Round 21
// baseline (36.395 us; speedup 1.0000x reference)
//
#include <hip/hip_runtime.h>
#include <cstdint>

// EdgeGateAttention, MI355X — round 21: champion (r14/r20, 35.1us) with ONE
// change: exp-port balancing.  Half the score-pairs evaluate via v_exp_f32
// (quarter-rate trans, ~4 issue-cyc/wave64), half via deg-3 Taylor exp2 on
// float2 with __builtin_elementwise_fma (v_pk_fma_f32, full-rate VALU).
// Theory: trans ops share the VALU issue port; 16 exps/iter = ~64 issue-cyc
// is the largest issue block.  r9's FULL-poly test overloaded VALU instead
// (and used risky inline-asm); balancing should cut the bottleneck port.
// Numerics: |s'|<=0.4 -> deg-3 rel err <=2.5e-4, and l sums the SAME approx
// P values so normalization cancels most of it (<< bf16-P quantization).
//
// Gate skip (validated r1): gate renorm makes it identity to O(1e-8).
// 0.25*log2(e) folded into Q.  l from ones-column (d=16) of the PV MFMA.

namespace {
constexpr int B  = 2;
constexpr int C  = 64;
constexpr int NH = 4;
constexpr int HD = 16;
constexpr int N  = 4096;
constexpr int MSA = 4;              // attention m-split
constexpr int MT  = 256;            // K/V m-tile rows staged in LDS
constexpr int VROW  = 2 * MT + 16;  // 528 B
constexpr int KSZ   = MT * 32;      // 8192 B
constexpr int BUFSZ = KSZ + HD * VROW;  // 16640 B

constexpr size_t QKV1     = (size_t)B * NH * N * HD;        // 524288
constexpr size_t KB_OFF   = QKV1;
constexpr size_t VT_OFF   = 2 * QKV1;
constexpr size_t PO_OFF_U = 3 * QKV1;                       // ushort idx
constexpr size_t PO_SZ    = (size_t)B * NH * MSA * N * HD;  // 2097152 ushorts
constexpr size_t PL_OFF_F = (PO_OFF_U + PO_SZ) / 2;         // float idx
constexpr float QSCALE = 0.36067376022224085f;              // 0.25 * log2(e)
// exp2 deg-3 Taylor: 2^x = 1 + x ln2 + (x ln2)^2/2 + (x ln2)^3/6
constexpr float PC1 = 0.6931471805599453f;
constexpr float PC2 = 0.2402265069591007f;
constexpr float PC3 = 0.05550410866482158f;
}

typedef short bf16x8 __attribute__((ext_vector_type(8)));
typedef float f32x16 __attribute__((ext_vector_type(16)));
typedef float f32x2  __attribute__((ext_vector_type(2)));
typedef int   i32x4  __attribute__((ext_vector_type(4)));

__device__ __forceinline__ unsigned short f2bf(float f) {  // RNE f32->bf16
  unsigned u = __float_as_uint(f);
  u = (u + 0x7fffu + ((u >> 16) & 1u)) >> 16;
  return (unsigned short)u;
}
__device__ __forceinline__ int cvtpk(float lo, float hi) {
  int r;
  asm("v_cvt_pk_bf16_f32 %0, %1, %2" : "=v"(r) : "v"(lo), "v"(hi));
  return r;
}
__device__ __forceinline__ float fexp2(float x) {  // raw v_exp_f32
#if __has_builtin(__builtin_amdgcn_exp2f)
  return __builtin_amdgcn_exp2f(x);
#else
  float r;
  asm("v_exp_f32 %0, %1" : "=v"(r) : "v"(x));
  return r;
#endif
}
__device__ __forceinline__ float frcp(float x) {
#if __has_builtin(__builtin_amdgcn_rcpf)
  return __builtin_amdgcn_rcpf(x);
#else
  float r;
  asm("v_rcp_f32 %0, %1" : "=v"(r) : "v"(x));
  return r;
#endif
}
__device__ __forceinline__ void plswap(int a, int b, int h, int& x, int& y) {
#if __has_builtin(__builtin_amdgcn_permlane32_swap)
  (void)h;
  auto r = __builtin_amdgcn_permlane32_swap(a, b, false, false);
  x = r[0]; y = r[1];
#else
  const int ea = __shfl_xor(a, 32), eb = __shfl_xor(b, 32);
  x = h ? eb : a;
  y = h ? b : ea;
#endif
}

// ---------------------------------------------------------------------------
// Kernel 1: QKV GEMM (champion).  Grid (N/64, B, 3): z=0 q, 1 k, 2 v.
// k output in LDS-read chunk order [bh][n/32][half][n%32] (16B chunks).
// ---------------------------------------------------------------------------
__global__ __launch_bounds__(256) void qkv_mfma_kernel(
    const float* __restrict__ x, const float* __restrict__ w,
    const float* __restrict__ bias, unsigned short* __restrict__ qb,
    unsigned short* __restrict__ kb, unsigned short* __restrict__ vtb) {
  __shared__ char wl[64 * 128];   // W slice bf16, byte (2c)^((j&7)<<4)
  __shared__ char tl[4 * 2048];   // per-wave transpose buffers
  const int tid = threadIdx.x;
  const int lane = tid & 63, wid = tid >> 6;
  const int l31 = lane & 31, h = lane >> 5;
  const int nw = wid >> 1, jw = wid & 1;
  const int b = blockIdx.y, n0 = blockIdx.x * 64, z = blockIdx.z;

#pragma unroll
  for (int k = 0; k < 8; ++k) {   // stage W slice (64 rows x 64 c)
    const int p = tid + k * 256;
    const int j = p >> 5, c2 = (p & 31) * 2;
    const float2 wv = *(const float2*)(w + ((size_t)z * 64 + j) * 64 + c2);
    *(int*)(wl + j * 128 + ((2 * c2) ^ ((j & 7) << 4))) = cvtpk(wv.x, wv.y);
  }

  const int nA = n0 + nw * 32 + l31;
  bf16x8 af[4];
#pragma unroll
  for (int kk = 0; kk < 4; ++kk) {  // A-frags from global (coalesced over n)
    float e[8];
#pragma unroll
    for (int i = 0; i < 8; ++i)
      e[i] = x[((size_t)b * C + kk * 16 + h * 8 + i) * N + nA];
    i32x4 pk = {cvtpk(e[0], e[1]), cvtpk(e[2], e[3]),
                cvtpk(e[4], e[5]), cvtpk(e[6], e[7])};
    af[kk] = __builtin_bit_cast(bf16x8, pk);
  }
  __syncthreads();

  const int j = jw * 32 + l31;      // j within z-slice (0..63)
  f32x16 acc = {};
#pragma unroll
  for (int kk = 0; kk < 4; ++kk) {
    bf16x8 bf =
        *(const bf16x8*)(wl + j * 128 + ((kk * 32 + h * 16) ^ ((j & 7) << 4)));
    acc = __builtin_amdgcn_mfma_f32_32x32x16_bf16(af[kk], bf, acc, 0, 0, 0);
  }
  const float bj = bias[z * 64 + j];
  char* myt = tl + wid * 2048;

  if (z < 2) {  // q/k; LDS [32n][32j] bf16 (rows 64B)
    const float sc = (z == 0) ? QSCALE : 1.0f;
#pragma unroll
    for (int r = 0; r < 16; ++r) {
      const int n = (r & 3) + 8 * (r >> 2) + 4 * h;
      *(unsigned short*)(myt + n * 64 + l31 * 2) = f2bf((acc[r] + bj) * sc);
    }
#pragma unroll
    for (int u = 0; u < 2; ++u) {   // 128 chunks: (n, 8-j group)
      const int chunk = lane * 2 + u;
      const int n = chunk >> 2, c = chunk & 3;
      const uint4 vv = *(const uint4*)(myt + n * 64 + c * 16);
      const int jj = jw * 32 + c * 8;          // j-offset in 0..63
      const int hh = jj >> 4, half = (jj >> 3) & 1;
      const int bh = b * NH + hh;
      if (z == 0) {   // q: [bh][n][16]
        *(uint4*)(qb + ((size_t)bh * N + n0 + nw * 32 + n) * HD + half * 8) = vv;
      } else {        // k: chunk order [bh][tile32][half][r]
        const size_t ck = (size_t)bh * 8192 +
                          (size_t)((n0 >> 5) + nw) * 64 + half * 32 + n;
        *(uint4*)(kb + ck * 8) = vv;
      }
    }
  } else {      // v -> transposed [bh][d][N]; LDS [32j][32n] bf16
#pragma unroll
    for (int p = 0; p < 8; ++p) {
      const int r = 2 * p;
      const int n = (r & 3) + 8 * (r >> 2) + 4 * h;  // even
      *(int*)(myt + l31 * 64 + n * 2) = cvtpk(acc[r] + bj, acc[r + 1] + bj);
    }
#pragma unroll
    for (int u = 0; u < 2; ++u) {   // 128 chunks: (j, 8-n group)
      const int chunk = lane * 2 + u;
      const int jj = chunk >> 2, c = chunk & 3;
      const uint4 vv = *(const uint4*)(myt + jj * 64 + c * 16);
      const int vj = jw * 32 + jj;             // 0..63
      const int hh = vj >> 4, hd = vj & 15;
      *(uint4*)(vtb + ((size_t)(b * NH + hh) * HD + hd) * N + n0 + nw * 32 +
                c * 8) = vv;
    }
  }
}

// ---------------------------------------------------------------------------
// Kernel 2: attention (champion structure), exp port-balanced:
// pairs 0-3 via v_exp_f32 (trans), pairs 4-7 via deg-3 poly (pk-FMA VALU).
// ---------------------------------------------------------------------------
__global__ __launch_bounds__(256, 4) void attn_mfma_kernel(
    const unsigned short* __restrict__ qb, const unsigned short* __restrict__ kb,
    const unsigned short* __restrict__ vtb, unsigned short* __restrict__ part_o,
    float* __restrict__ part_l) {
  __shared__ uint4 ldsq[2 * BUFSZ / 16];
  char* ldsb = (char*)ldsq;
  const int tid  = threadIdx.x;
  const int lane = tid & 63;
  const int wid  = tid >> 6;
  const int l31  = lane & 31;
  const int h    = lane >> 5;
  const int bh = blockIdx.z;
  const int ms = blockIdx.y;
  const int q0 = blockIdx.x * 128 + wid * 32;
  const int m0 = ms * (N / MSA);
  constexpr int nt = (N / MSA) / MT;  // 4

  bf16x8 qf;
  {
    const uint4 qv =
        *(const uint4*)(qb + (((size_t)bh * N) + q0 + l31) * HD + h * 8);
    qf = __builtin_bit_cast(bf16x8, qv);
  }
  const unsigned short* kgp = kb + ((size_t)bh * 8192 + (m0 >> 5) * 64) * 8;
  const unsigned short* vgp = vtb + (size_t)bh * HD * N + m0;
  const int d0 = tid >> 5, c0 = tid & 31;
  const int d1 = d0 + 8;

  {
    uint4 k0 = *(const uint4*)(kgp + (size_t)tid * 8);
    uint4 k1 = *(const uint4*)(kgp + (size_t)(tid + 256) * 8);
    uint4 v0 = *(const uint4*)(vgp + (size_t)d0 * N + c0 * 8);
    uint4 v1 = *(const uint4*)(vgp + (size_t)d1 * N + c0 * 8);
    *(uint4*)(ldsb + tid * 16) = k0;
    *(uint4*)(ldsb + (tid + 256) * 16) = k1;
    *(uint4*)(ldsb + KSZ + d0 * VROW + c0 * 16) = v0;
    *(uint4*)(ldsb + KSZ + d1 * VROW + c0 * 16) = v1;
  }
  __syncthreads();

  // ones-column constant for lanes l31 >= 16 (l from PV accumulation)
  const int onef = (l31 == HD) ? 0x3F803F80 : 0;
  const i32x4 onev = {onef, onef, onef, onef};
  const bf16x8 vcst = __builtin_bit_cast(bf16x8, onev);
  const f32x2 vc1 = {PC1, PC1}, vc2 = {PC2, PC2}, vc3 = {PC3, PC3};
  const f32x2 vone = {1.0f, 1.0f};

  f32x16 acc = {};
  int cur = 0;
  for (int t = 0; t < nt; ++t) {
    uint4 k0{}, k1{}, v0{}, v1{};
    const bool pre = (t + 1 < nt);
    if (pre) {
      const unsigned short* kt = kgp + (size_t)(t + 1) * 512 * 8;
      const unsigned short* vt = vgp + (t + 1) * MT;
      k0 = *(const uint4*)(kt + (size_t)tid * 8);
      k1 = *(const uint4*)(kt + (size_t)(tid + 256) * 8);
      v0 = *(const uint4*)(vt + (size_t)d0 * N + c0 * 8);
      v1 = *(const uint4*)(vt + (size_t)d1 * N + c0 * 8);
    }
    const char* kbase = ldsb + cur * BUFSZ;
    const char* vbase = kbase + KSZ;

    // pipeline prologue: K-frag 0 + its QK^T
    bf16x8 kf = *(const bf16x8*)(kbase + (h * 32 + l31) * 16);
    f32x16 zv = {};
    f32x16 stn = __builtin_amdgcn_mfma_f32_32x32x16_bf16(kf, qf, zv, 0, 0, 0);

#pragma unroll
    for (int cc = 0; cc < MT / 32; ++cc) {
      const f32x16 st = stn;
      if (cc + 1 < MT / 32) {   // issue next K read + QK^T before processing
        bf16x8 kf2 =
            *(const bf16x8*)(kbase + ((cc + 1) * 64 + h * 32 + l31) * 16);
        stn = __builtin_amdgcn_mfma_f32_32x32x16_bf16(kf2, qf, zv, 0, 0, 0);
      }
      // V fragments (independent of st) — issue early
      bf16x8 vf1, vf2;
      if (l31 < HD) {
        const char* vrow = vbase + l31 * VROW + cc * 64 + h * 16;
        vf1 = *(const bf16x8*)(vrow);
        vf2 = *(const bf16x8*)(vrow + 32);
      } else {
        vf1 = vcst;
        vf2 = vcst;
      }
      int dw[8];
#pragma unroll
      for (int jj = 0; jj < 4; ++jj)   // trans-pipe half
        dw[jj] = cvtpk(fexp2(st[2 * jj]), fexp2(st[2 * jj + 1]));
#pragma unroll
      for (int jj = 4; jj < 8; ++jj) { // VALU half: deg-3 packed Taylor
        const f32x2 xp = {st[2 * jj], st[2 * jj + 1]};
        f32x2 tp = __builtin_elementwise_fma(vc3, xp, vc2);
        tp = __builtin_elementwise_fma(tp, xp, vc1);
        tp = __builtin_elementwise_fma(tp, xp, vone);
        dw[jj] = cvtpk(tp[0], tp[1]);
      }
      int w0, w1, w2, w3, w4, w5, w6, w7;
      plswap(dw[0], dw[2], h, w0, w2);
      plswap(dw[1], dw[3], h, w1, w3);
      plswap(dw[4], dw[6], h, w4, w6);
      plswap(dw[5], dw[7], h, w5, w7);
      const i32x4 a1 = {w0, w1, w2, w3};
      const i32x4 a2 = {w4, w5, w6, w7};
      acc = __builtin_amdgcn_mfma_f32_32x32x16_bf16(
          __builtin_bit_cast(bf16x8, a1), vf1, acc, 0, 0, 0);
      acc = __builtin_amdgcn_mfma_f32_32x32x16_bf16(
          __builtin_bit_cast(bf16x8, a2), vf2, acc, 0, 0, 0);
    }
    if (pre) {
      char* nb = ldsb + (cur ^ 1) * BUFSZ;
      *(uint4*)(nb + tid * 16) = k0;
      *(uint4*)(nb + (tid + 256) * 16) = k1;
      *(uint4*)(nb + KSZ + d0 * VROW + c0 * 16) = v0;
      *(uint4*)(nb + KSZ + d1 * VROW + c0 * 16) = v1;
    }
    __syncthreads();
    cur ^= 1;
  }

  const size_t pbase = ((size_t)bh * MSA + ms) * N + q0;
  if (l31 == HD) {
#pragma unroll
    for (int r = 0; r < 16; ++r)
      part_l[pbase + (r & 3) + 8 * (r >> 2) + 4 * h] = acc[r];
  }
  char* myt = ldsb + wid * 1024;
  if (l31 < HD) {
#pragma unroll
    for (int r = 0; r < 16; ++r) {
      const int q = (r & 3) + 8 * (r >> 2) + 4 * h;
      *(unsigned short*)(myt + q * 32 + l31 * 2) = f2bf(acc[r]);
    }
  }
  __syncthreads();
  const int qr = lane >> 1, half = lane & 1;
  const uint4 vv = *(const uint4*)(myt + qr * 32 + half * 16);
  *(uint4*)(part_o + (pbase + qr) * HD + half * 8) = vv;
}

// ---------------------------------------------------------------------------
// Kernel 3: fused combine + projection (champion).  Grid (N/32, B).
// ---------------------------------------------------------------------------
__global__ __launch_bounds__(128) void proj_mfma_kernel(
    const unsigned short* __restrict__ part_o, const float* __restrict__ part_l,
    const float* __restrict__ pw, const float* __restrict__ pb,
    float* __restrict__ out) {
  __shared__ char al[32 * 128];
  __shared__ char bl[64 * 128];
  __shared__ char tl[2 * 4096];
  __shared__ float linv[128];
  const int tid = threadIdx.x;
  const int lane = tid & 63, wid = tid >> 6;
  const int l31 = lane & 31, h = lane >> 5;
  const int b = blockIdx.y, n0 = blockIdx.x * 32;

  {
    const int hh = tid >> 5, n = tid & 31;
    const size_t base = ((size_t)(b * NH + hh) * MSA) * N + n0 + n;
    float l = 0.f;
#pragma unroll
    for (int ms = 0; ms < MSA; ++ms) l += part_l[base + (size_t)ms * N];
    linv[tid] = frcp(l);
  }
#pragma unroll
  for (int k = 0; k < 16; ++k) {
    const int p = tid + k * 128;
    const int cR = p >> 5, d2 = (p & 31) * 2;
    const float2 wv = *(const float2*)(pw + cR * 64 + d2);
    *(int*)(bl + cR * 128 + ((2 * d2) ^ ((cR & 7) << 4))) = cvtpk(wv.x, wv.y);
  }
  __syncthreads();

#pragma unroll
  for (int u = 0; u < 2; ++u) {
    const int chunk = tid * 2 + u;
    const int hh = chunk >> 6, half = (chunk >> 5) & 1, n = chunk & 31;
    const unsigned short* src =
        part_o + (((size_t)(b * NH + hh) * MSA) * N + n0 + n) * HD + half * 8;
    float s[8] = {0.f, 0.f, 0.f, 0.f, 0.f, 0.f, 0.f, 0.f};
#pragma unroll
    for (int ms = 0; ms < MSA; ++ms) {
      const uint4 v = *(const uint4*)(src + (size_t)ms * N * HD);
      const unsigned uu[4] = {v.x, v.y, v.z, v.w};
#pragma unroll
      for (int q = 0; q < 4; ++q) {
        s[2 * q]     += __uint_as_float(uu[q] << 16);
        s[2 * q + 1] += __uint_as_float(uu[q] & 0xffff0000u);
      }
    }
    const float iv = linv[hh * 32 + n];
    const i32x4 pk = {cvtpk(s[0] * iv, s[1] * iv), cvtpk(s[2] * iv, s[3] * iv),
                      cvtpk(s[4] * iv, s[5] * iv), cvtpk(s[6] * iv, s[7] * iv)};
    const int d = hh * 16 + half * 8;
    *(i32x4*)(al + n * 128 + ((2 * d) ^ ((n & 7) << 4))) = pk;
  }
  __syncthreads();

  bf16x8 af[4];
#pragma unroll
  for (int kk = 0; kk < 4; ++kk)
    af[kk] = *(const bf16x8*)(al + l31 * 128 +
                              ((kk * 32 + h * 16) ^ ((l31 & 7) << 4)));
  const int c = wid * 32 + l31;
  f32x16 acc = {};
#pragma unroll
  for (int kk = 0; kk < 4; ++kk) {
    bf16x8 bf =
        *(const bf16x8*)(bl + c * 128 + ((kk * 32 + h * 16) ^ ((c & 7) << 4)));
    acc = __builtin_amdgcn_mfma_f32_32x32x16_bf16(af[kk], bf, acc, 0, 0, 0);
  }
  const float bc = pb[c];

  char* myt = tl + wid * 4096;
#pragma unroll
  for (int p = 0; p < 8; ++p) {
    const int r = 2 * p;
    const int n = (r & 3) + 8 * (r >> 2) + 4 * h;
    *(float2*)(myt + l31 * 128 + n * 4) =
        make_float2(acc[r] + bc, acc[r + 1] + bc);
  }
  __syncthreads();
#pragma unroll
  for (int u = 0; u < 4; ++u) {
    const int chunk = lane * 4 + u;
    const int cc = chunk >> 3, cq = chunk & 7;
    const float4 vv = *(const float4*)(myt + cc * 128 + cq * 16);
    *(float4*)(out + ((size_t)b * C + wid * 32 + cc) * N + n0 + cq * 4) = vv;
  }
}

// ---------------------------------------------------------------------------
extern "C" void kernel_launch(void* const* d_in, const int* in_sizes, int n_in,
                              void* d_out, int out_size, void* d_ws, size_t ws_size,
                              hipStream_t stream) {
  const float* x      = (const float*)d_in[0];
  const float* qkv_w  = (const float*)d_in[1];
  const float* qkv_b  = (const float*)d_in[2];
  const float* proj_w = (const float*)d_in[3];
  const float* proj_b = (const float*)d_in[4];
  // d_in[5..8] (gate MLP) intentionally unused — see header note.
  unsigned short* qb     = (unsigned short*)d_ws;
  unsigned short* kb     = qb + KB_OFF;
  unsigned short* vtb    = qb + VT_OFF;
  unsigned short* part_o = qb + PO_OFF_U;
  float* part_l = (float*)d_ws + PL_OFF_F;
  float* out = (float*)d_out;

  qkv_mfma_kernel<<<dim3(N / 64, B, 3), 256, 0, stream>>>(
      x, qkv_w, qkv_b, qb, kb, vtb);
  attn_mfma_kernel<<<dim3(N / 128, MSA, B * NH), 256, 0, stream>>>(
      qb, kb, vtb, part_o, part_l);
  proj_mfma_kernel<<<dim3(N / 32, B), 128, 0, stream>>>(
      part_o, part_l, proj_w, proj_b, out);
}

// Round 22
// 34.910 us; speedup vs baseline: 1.0425x; 1.0425x over previous
//
#include <hip/hip_runtime.h>
#include <cstdint>

// EdgeGateAttention, MI355X — FINAL: the round-14/20 champion (35.05/35.15us,
// best of 21 rounds; r21 port-balance +1.3us -> reverted).
// Config: MSA=4 (1024 blocks, 4 waves/SIMD), MT=256 K+V LDS double-buffer,
// chunk-ordered conflict-free K, software-pipelined inner loop, (256,4);
// bf16 partials; fused combine+proj.  Session: 181 -> ~35us (5.2x).
// Falsified along the way: trans-bound (poly swap neutral), latency-via-
// occupancy (5w regressed), 2-tile ILP (spilled), LDS-free (L2 latency),
// grid-barrier fusion (spin-dominated), port-balancing (neutral).
// Only material attn win: LDS bank-conflict fix via chunk-ordered K (-5.5us).
//
// Gate skip (validated r1): gate renorm makes it identity to O(1e-8).
// Softmax: raw v_exp_f32, no max subtraction; 0.25*log2(e) folded into Q.
// l from ones-column (d=16) of the PV MFMA.

namespace {
constexpr int B  = 2;
constexpr int C  = 64;
constexpr int NH = 4;
constexpr int HD = 16;
constexpr int N  = 4096;
constexpr int MSA = 4;              // attention m-split
constexpr int MT  = 256;            // K/V m-tile rows staged in LDS
constexpr int VROW  = 2 * MT + 16;  // 528 B
constexpr int KSZ   = MT * 32;      // 8192 B
constexpr int BUFSZ = KSZ + HD * VROW;  // 16640 B

constexpr size_t QKV1     = (size_t)B * NH * N * HD;        // 524288
constexpr size_t KB_OFF   = QKV1;
constexpr size_t VT_OFF   = 2 * QKV1;
constexpr size_t PO_OFF_U = 3 * QKV1;                       // ushort idx
constexpr size_t PO_SZ    = (size_t)B * NH * MSA * N * HD;  // 2097152 ushorts
constexpr size_t PL_OFF_F = (PO_OFF_U + PO_SZ) / 2;         // float idx
constexpr float QSCALE = 0.36067376022224085f;              // 0.25 * log2(e)
}

typedef short bf16x8 __attribute__((ext_vector_type(8)));
typedef float f32x16 __attribute__((ext_vector_type(16)));
typedef int   i32x4  __attribute__((ext_vector_type(4)));

__device__ __forceinline__ unsigned short f2bf(float f) {  // RNE f32->bf16
  unsigned u = __float_as_uint(f);
  u = (u + 0x7fffu + ((u >> 16) & 1u)) >> 16;
  return (unsigned short)u;
}
__device__ __forceinline__ int cvtpk(float lo, float hi) {
  int r;
  asm("v_cvt_pk_bf16_f32 %0, %1, %2" : "=v"(r) : "v"(lo), "v"(hi));
  return r;
}
__device__ __forceinline__ float fexp2(float x) {  // raw v_exp_f32
#if __has_builtin(__builtin_amdgcn_exp2f)
  return __builtin_amdgcn_exp2f(x);
#else
  float r;
  asm("v_exp_f32 %0, %1" : "=v"(r) : "v"(x));
  return r;
#endif
}
__device__ __forceinline__ float frcp(float x) {
#if __has_builtin(__builtin_amdgcn_rcpf)
  return __builtin_amdgcn_rcpf(x);
#else
  float r;
  asm("v_rcp_f32 %0, %1" : "=v"(r) : "v"(x));
  return r;
#endif
}
__device__ __forceinline__ void plswap(int a, int b, int h, int& x, int& y) {
#if __has_builtin(__builtin_amdgcn_permlane32_swap)
  (void)h;
  auto r = __builtin_amdgcn_permlane32_swap(a, b, false, false);
  x = r[0]; y = r[1];
#else
  const int ea = __shfl_xor(a, 32), eb = __shfl_xor(b, 32);
  x = h ? eb : a;
  y = h ? b : ea;
#endif
}

// ---------------------------------------------------------------------------
// Kernel 1: QKV GEMM.  Grid (N/64, B, 3): z=0 q, 1 k, 2 v.
// k output in LDS-read chunk order [bh][n/32][half][n%32] (16B chunks).
// ---------------------------------------------------------------------------
__global__ __launch_bounds__(256) void qkv_mfma_kernel(
    const float* __restrict__ x, const float* __restrict__ w,
    const float* __restrict__ bias, unsigned short* __restrict__ qb,
    unsigned short* __restrict__ kb, unsigned short* __restrict__ vtb) {
  __shared__ char wl[64 * 128];   // W slice bf16, byte (2c)^((j&7)<<4)
  __shared__ char tl[4 * 2048];   // per-wave transpose buffers
  const int tid = threadIdx.x;
  const int lane = tid & 63, wid = tid >> 6;
  const int l31 = lane & 31, h = lane >> 5;
  const int nw = wid >> 1, jw = wid & 1;
  const int b = blockIdx.y, n0 = blockIdx.x * 64, z = blockIdx.z;

#pragma unroll
  for (int k = 0; k < 8; ++k) {   // stage W slice (64 rows x 64 c)
    const int p = tid + k * 256;
    const int j = p >> 5, c2 = (p & 31) * 2;
    const float2 wv = *(const float2*)(w + ((size_t)z * 64 + j) * 64 + c2);
    *(int*)(wl + j * 128 + ((2 * c2) ^ ((j & 7) << 4))) = cvtpk(wv.x, wv.y);
  }

  const int nA = n0 + nw * 32 + l31;
  bf16x8 af[4];
#pragma unroll
  for (int kk = 0; kk < 4; ++kk) {  // A-frags from global (coalesced over n)
    float e[8];
#pragma unroll
    for (int i = 0; i < 8; ++i)
      e[i] = x[((size_t)b * C + kk * 16 + h * 8 + i) * N + nA];
    i32x4 pk = {cvtpk(e[0], e[1]), cvtpk(e[2], e[3]),
                cvtpk(e[4], e[5]), cvtpk(e[6], e[7])};
    af[kk] = __builtin_bit_cast(bf16x8, pk);
  }
  __syncthreads();

  const int j = jw * 32 + l31;      // j within z-slice (0..63)
  f32x16 acc = {};
#pragma unroll
  for (int kk = 0; kk < 4; ++kk) {
    bf16x8 bf =
        *(const bf16x8*)(wl + j * 128 + ((kk * 32 + h * 16) ^ ((j & 7) << 4)));
    acc = __builtin_amdgcn_mfma_f32_32x32x16_bf16(af[kk], bf, acc, 0, 0, 0);
  }
  const float bj = bias[z * 64 + j];
  char* myt = tl + wid * 2048;

  if (z < 2) {  // q/k; LDS [32n][32j] bf16 (rows 64B)
    const float sc = (z == 0) ? QSCALE : 1.0f;
#pragma unroll
    for (int r = 0; r < 16; ++r) {
      const int n = (r & 3) + 8 * (r >> 2) + 4 * h;
      *(unsigned short*)(myt + n * 64 + l31 * 2) = f2bf((acc[r] + bj) * sc);
    }
#pragma unroll
    for (int u = 0; u < 2; ++u) {   // 128 chunks: (n, 8-j group)
      const int chunk = lane * 2 + u;
      const int n = chunk >> 2, c = chunk & 3;
      const uint4 vv = *(const uint4*)(myt + n * 64 + c * 16);
      const int jj = jw * 32 + c * 8;          // j-offset in 0..63
      const int hh = jj >> 4, half = (jj >> 3) & 1;
      const int bh = b * NH + hh;
      if (z == 0) {   // q: [bh][n][16]
        *(uint4*)(qb + ((size_t)bh * N + n0 + nw * 32 + n) * HD + half * 8) = vv;
      } else {        // k: chunk order [bh][tile32][half][r]
        const size_t ck = (size_t)bh * 8192 +
                          (size_t)((n0 >> 5) + nw) * 64 + half * 32 + n;
        *(uint4*)(kb + ck * 8) = vv;
      }
    }
  } else {      // v -> transposed [bh][d][N]; LDS [32j][32n] bf16
#pragma unroll
    for (int p = 0; p < 8; ++p) {
      const int r = 2 * p;
      const int n = (r & 3) + 8 * (r >> 2) + 4 * h;  // even
      *(int*)(myt + l31 * 64 + n * 2) = cvtpk(acc[r] + bj, acc[r + 1] + bj);
    }
#pragma unroll
    for (int u = 0; u < 2; ++u) {   // 128 chunks: (j, 8-n group)
      const int chunk = lane * 2 + u;
      const int jj = chunk >> 2, c = chunk & 3;
      const uint4 vv = *(const uint4*)(myt + jj * 64 + c * 16);
      const int vj = jw * 32 + jj;             // 0..63
      const int hh = vj >> 4, hd = vj & 15;
      *(uint4*)(vtb + ((size_t)(b * NH + hh) * HD + hd) * N + n0 + nw * 32 +
                c * 8) = vv;
    }
  }
}

// ---------------------------------------------------------------------------
// Kernel 2: attention, software-pipelined.  Grid (N/128, MSA, B*NH) = 1024.
// Conflict-free K path (chunk-ordered kb); next iter's K read + QK^T MFMA
// issued before current iter's exp/pack/PV processing.
// ---------------------------------------------------------------------------
__global__ __launch_bounds__(256, 4) void attn_mfma_kernel(
    const unsigned short* __restrict__ qb, const unsigned short* __restrict__ kb,
    const unsigned short* __restrict__ vtb, unsigned short* __restrict__ part_o,
    float* __restrict__ part_l) {
  __shared__ uint4 ldsq[2 * BUFSZ / 16];
  char* ldsb = (char*)ldsq;
  const int tid  = threadIdx.x;
  const int lane = tid & 63;
  const int wid  = tid >> 6;
  const int l31  = lane & 31;
  const int h    = lane >> 5;
  const int bh = blockIdx.z;
  const int ms = blockIdx.y;
  const int q0 = blockIdx.x * 128 + wid * 32;
  const int m0 = ms * (N / MSA);
  constexpr int nt = (N / MSA) / MT;  // 4

  bf16x8 qf;
  {
    const uint4 qv =
        *(const uint4*)(qb + (((size_t)bh * N) + q0 + l31) * HD + h * 8);
    qf = __builtin_bit_cast(bf16x8, qv);
  }
  const unsigned short* kgp = kb + ((size_t)bh * 8192 + (m0 >> 5) * 64) * 8;
  const unsigned short* vgp = vtb + (size_t)bh * HD * N + m0;
  const int d0 = tid >> 5, c0 = tid & 31;
  const int d1 = d0 + 8;

  {
    uint4 k0 = *(const uint4*)(kgp + (size_t)tid * 8);
    uint4 k1 = *(const uint4*)(kgp + (size_t)(tid + 256) * 8);
    uint4 v0 = *(const uint4*)(vgp + (size_t)d0 * N + c0 * 8);
    uint4 v1 = *(const uint4*)(vgp + (size_t)d1 * N + c0 * 8);
    *(uint4*)(ldsb + tid * 16) = k0;
    *(uint4*)(ldsb + (tid + 256) * 16) = k1;
    *(uint4*)(ldsb + KSZ + d0 * VROW + c0 * 16) = v0;
    *(uint4*)(ldsb + KSZ + d1 * VROW + c0 * 16) = v1;
  }
  __syncthreads();

  // ones-column constant for lanes l31 >= 16 (l from PV accumulation)
  const int onef = (l31 == HD) ? 0x3F803F80 : 0;
  const i32x4 onev = {onef, onef, onef, onef};
  const bf16x8 vcst = __builtin_bit_cast(bf16x8, onev);

  f32x16 acc = {};
  int cur = 0;
  for (int t = 0; t < nt; ++t) {
    uint4 k0{}, k1{}, v0{}, v1{};
    const bool pre = (t + 1 < nt);
    if (pre) {
      const unsigned short* kt = kgp + (size_t)(t + 1) * 512 * 8;
      const unsigned short* vt = vgp + (t + 1) * MT;
      k0 = *(const uint4*)(kt + (size_t)tid * 8);
      k1 = *(const uint4*)(kt + (size_t)(tid + 256) * 8);
      v0 = *(const uint4*)(vt + (size_t)d0 * N + c0 * 8);
      v1 = *(const uint4*)(vt + (size_t)d1 * N + c0 * 8);
    }
    const char* kbase = ldsb + cur * BUFSZ;
    const char* vbase = kbase + KSZ;

    // pipeline prologue: K-frag 0 + its QK^T
    bf16x8 kf = *(const bf16x8*)(kbase + (h * 32 + l31) * 16);
    f32x16 zv = {};
    f32x16 stn = __builtin_amdgcn_mfma_f32_32x32x16_bf16(kf, qf, zv, 0, 0, 0);

#pragma unroll
    for (int cc = 0; cc < MT / 32; ++cc) {
      const f32x16 st = stn;
      if (cc + 1 < MT / 32) {   // issue next K read + QK^T before processing
        bf16x8 kf2 =
            *(const bf16x8*)(kbase + ((cc + 1) * 64 + h * 32 + l31) * 16);
        stn = __builtin_amdgcn_mfma_f32_32x32x16_bf16(kf2, qf, zv, 0, 0, 0);
      }
      // V fragments (independent of st) — issue early
      bf16x8 vf1, vf2;
      if (l31 < HD) {
        const char* vrow = vbase + l31 * VROW + cc * 64 + h * 16;
        vf1 = *(const bf16x8*)(vrow);
        vf2 = *(const bf16x8*)(vrow + 32);
      } else {
        vf1 = vcst;
        vf2 = vcst;
      }
      int dw[8];
#pragma unroll
      for (int jj = 0; jj < 8; ++jj)   // exp -> pack, pairwise (short lives)
        dw[jj] = cvtpk(fexp2(st[2 * jj]), fexp2(st[2 * jj + 1]));
      int w0, w1, w2, w3, w4, w5, w6, w7;
      plswap(dw[0], dw[2], h, w0, w2);
      plswap(dw[1], dw[3], h, w1, w3);
      plswap(dw[4], dw[6], h, w4, w6);
      plswap(dw[5], dw[7], h, w5, w7);
      const i32x4 a1 = {w0, w1, w2, w3};
      const i32x4 a2 = {w4, w5, w6, w7};
      acc = __builtin_amdgcn_mfma_f32_32x32x16_bf16(
          __builtin_bit_cast(bf16x8, a1), vf1, acc, 0, 0, 0);
      acc = __builtin_amdgcn_mfma_f32_32x32x16_bf16(
          __builtin_bit_cast(bf16x8, a2), vf2, acc, 0, 0, 0);
    }
    if (pre) {
      char* nb = ldsb + (cur ^ 1) * BUFSZ;
      *(uint4*)(nb + tid * 16) = k0;
      *(uint4*)(nb + (tid + 256) * 16) = k1;
      *(uint4*)(nb + KSZ + d0 * VROW + c0 * 16) = v0;
      *(uint4*)(nb + KSZ + d1 * VROW + c0 * 16) = v1;
    }
    __syncthreads();
    cur ^= 1;
  }

  const size_t pbase = ((size_t)bh * MSA + ms) * N + q0;
  if (l31 == HD) {
#pragma unroll
    for (int r = 0; r < 16; ++r)
      part_l[pbase + (r & 3) + 8 * (r >> 2) + 4 * h] = acc[r];
  }
  char* myt = ldsb + wid * 1024;
  if (l31 < HD) {
#pragma unroll
    for (int r = 0; r < 16; ++r) {
      const int q = (r & 3) + 8 * (r >> 2) + 4 * h;
      *(unsigned short*)(myt + q * 32 + l31 * 2) = f2bf(acc[r]);
    }
  }
  __syncthreads();
  const int qr = lane >> 1, half = lane & 1;
  const uint4 vv = *(const uint4*)(myt + qr * 32 + half * 16);
  *(uint4*)(part_o + (pbase + qr) * HD + half * 8) = vv;
}

// ---------------------------------------------------------------------------
// Kernel 3: fused combine + projection.  Grid (N/32, B), 128 thr / 2 waves.
// ---------------------------------------------------------------------------
__global__ __launch_bounds__(128) void proj_mfma_kernel(
    const unsigned short* __restrict__ part_o, const float* __restrict__ part_l,
    const float* __restrict__ pw, const float* __restrict__ pb,
    float* __restrict__ out) {
  __shared__ char al[32 * 128];
  __shared__ char bl[64 * 128];
  __shared__ char tl[2 * 4096];
  __shared__ float linv[128];
  const int tid = threadIdx.x;
  const int lane = tid & 63, wid = tid >> 6;
  const int l31 = lane & 31, h = lane >> 5;
  const int b = blockIdx.y, n0 = blockIdx.x * 32;

  {
    const int hh = tid >> 5, n = tid & 31;
    const size_t base = ((size_t)(b * NH + hh) * MSA) * N + n0 + n;
    float l = 0.f;
#pragma unroll
    for (int ms = 0; ms < MSA; ++ms) l += part_l[base + (size_t)ms * N];
    linv[tid] = frcp(l);
  }
#pragma unroll
  for (int k = 0; k < 16; ++k) {
    const int p = tid + k * 128;
    const int cR = p >> 5, d2 = (p & 31) * 2;
    const float2 wv = *(const float2*)(pw + cR * 64 + d2);
    *(int*)(bl + cR * 128 + ((2 * d2) ^ ((cR & 7) << 4))) = cvtpk(wv.x, wv.y);
  }
  __syncthreads();

#pragma unroll
  for (int u = 0; u < 2; ++u) {
    const int chunk = tid * 2 + u;
    const int hh = chunk >> 6, half = (chunk >> 5) & 1, n = chunk & 31;
    const unsigned short* src =
        part_o + (((size_t)(b * NH + hh) * MSA) * N + n0 + n) * HD + half * 8;
    float s[8] = {0.f, 0.f, 0.f, 0.f, 0.f, 0.f, 0.f, 0.f};
#pragma unroll
    for (int ms = 0; ms < MSA; ++ms) {
      const uint4 v = *(const uint4*)(src + (size_t)ms * N * HD);
      const unsigned uu[4] = {v.x, v.y, v.z, v.w};
#pragma unroll
      for (int q = 0; q < 4; ++q) {
        s[2 * q]     += __uint_as_float(uu[q] << 16);
        s[2 * q + 1] += __uint_as_float(uu[q] & 0xffff0000u);
      }
    }
    const float iv = linv[hh * 32 + n];
    const i32x4 pk = {cvtpk(s[0] * iv, s[1] * iv), cvtpk(s[2] * iv, s[3] * iv),
                      cvtpk(s[4] * iv, s[5] * iv), cvtpk(s[6] * iv, s[7] * iv)};
    const int d = hh * 16 + half * 8;
    *(i32x4*)(al + n * 128 + ((2 * d) ^ ((n & 7) << 4))) = pk;
  }
  __syncthreads();

  bf16x8 af[4];
#pragma unroll
  for (int kk = 0; kk < 4; ++kk)
    af[kk] = *(const bf16x8*)(al + l31 * 128 +
                              ((kk * 32 + h * 16) ^ ((l31 & 7) << 4)));
  const int c = wid * 32 + l31;
  f32x16 acc = {};
#pragma unroll
  for (int kk = 0; kk < 4; ++kk) {
    bf16x8 bf =
        *(const bf16x8*)(bl + c * 128 + ((kk * 32 + h * 16) ^ ((c & 7) << 4)));
    acc = __builtin_amdgcn_mfma_f32_32x32x16_bf16(af[kk], bf, acc, 0, 0, 0);
  }
  const float bc = pb[c];

  char* myt = tl + wid * 4096;
#pragma unroll
  for (int p = 0; p < 8; ++p) {
    const int r = 2 * p;
    const int n = (r & 3) + 8 * (r >> 2) + 4 * h;
    *(float2*)(myt + l31 * 128 + n * 4) =
        make_float2(acc[r] + bc, acc[r + 1] + bc);
  }
  __syncthreads();
#pragma unroll
  for (int u = 0; u < 4; ++u) {
    const int chunk = lane * 4 + u;
    const int cc = chunk >> 3, cq = chunk & 7;
    const float4 vv = *(const float4*)(myt + cc * 128 + cq * 16);
    *(float4*)(out + ((size_t)b * C + wid * 32 + cc) * N + n0 + cq * 4) = vv;
  }
}

// ---------------------------------------------------------------------------
extern "C" void kernel_launch(void* const* d_in, const int* in_sizes, int n_in,
                              void* d_out, int out_size, void* d_ws, size_t ws_size,
                              hipStream_t stream) {
  const float* x      = (const float*)d_in[0];
  const float* qkv_w  = (const float*)d_in[1];
  const float* qkv_b  = (const float*)d_in[2];
  const float* proj_w = (const float*)d_in[3];
  const float* proj_b = (const float*)d_in[4];
  // d_in[5..8] (gate MLP) intentionally unused — see header note.
  unsigned short* qb     = (unsigned short*)d_ws;
  unsigned short* kb     = qb + KB_OFF;
  unsigned short* vtb    = qb + VT_OFF;
  unsigned short* part_o = qb + PO_OFF_U;
  float* part_l = (float*)d_ws + PL_OFF_F;
  float* out = (float*)d_out;

  qkv_mfma_kernel<<<dim3(N / 64, B, 3), 256, 0, stream>>>(
      x, qkv_w, qkv_b, qb, kb, vtb);
  attn_mfma_kernel<<<dim3(N / 128, MSA, B * NH), 256, 0, stream>>>(
      qb, kb, vtb, part_o, part_l);
  proj_mfma_kernel<<<dim3(N / 32, B), 128, 0, stream>>>(
      part_o, part_l, proj_w, proj_b, out);
}

// Round 23
// 34.838 us; speedup vs baseline: 1.0447x; 1.0021x over previous
//
#include <hip/hip_runtime.h>
#include <cstdint>

// EdgeGateAttention, MI355X — round 23: champion (34.91us, 3x reproduced)
// with ONE change: proj k-split.  Old proj = 256 blk x 2 waves = 0.5
// waves/SIMD (latency-exposed).  New proj = 256 blk x 4 waves (2 c-tiles x
// 2 k-halves + 16KB LDS reduce — structure lifted from r10's phase 3, which
// passed with identical absmax).  qkv + attn byte-identical to champion.
//
// Gate skip (validated r1): gate renorm makes it identity to O(1e-8).
// Softmax: raw v_exp_f32, no max subtraction; 0.25*log2(e) folded into Q.
// l from ones-column (d=16) of the PV MFMA.

namespace {
constexpr int B  = 2;
constexpr int C  = 64;
constexpr int NH = 4;
constexpr int HD = 16;
constexpr int N  = 4096;
constexpr int MSA = 4;              // attention m-split
constexpr int MT  = 256;            // K/V m-tile rows staged in LDS
constexpr int VROW  = 2 * MT + 16;  // 528 B
constexpr int KSZ   = MT * 32;      // 8192 B
constexpr int BUFSZ = KSZ + HD * VROW;  // 16640 B

constexpr size_t QKV1     = (size_t)B * NH * N * HD;        // 524288
constexpr size_t KB_OFF   = QKV1;
constexpr size_t VT_OFF   = 2 * QKV1;
constexpr size_t PO_OFF_U = 3 * QKV1;                       // ushort idx
constexpr size_t PO_SZ    = (size_t)B * NH * MSA * N * HD;  // 2097152 ushorts
constexpr size_t PL_OFF_F = (PO_OFF_U + PO_SZ) / 2;         // float idx
constexpr float QSCALE = 0.36067376022224085f;              // 0.25 * log2(e)
}

typedef short bf16x8 __attribute__((ext_vector_type(8)));
typedef float f32x16 __attribute__((ext_vector_type(16)));
typedef int   i32x4  __attribute__((ext_vector_type(4)));

__device__ __forceinline__ unsigned short f2bf(float f) {  // RNE f32->bf16
  unsigned u = __float_as_uint(f);
  u = (u + 0x7fffu + ((u >> 16) & 1u)) >> 16;
  return (unsigned short)u;
}
__device__ __forceinline__ int cvtpk(float lo, float hi) {
  int r;
  asm("v_cvt_pk_bf16_f32 %0, %1, %2" : "=v"(r) : "v"(lo), "v"(hi));
  return r;
}
__device__ __forceinline__ float fexp2(float x) {  // raw v_exp_f32
#if __has_builtin(__builtin_amdgcn_exp2f)
  return __builtin_amdgcn_exp2f(x);
#else
  float r;
  asm("v_exp_f32 %0, %1" : "=v"(r) : "v"(x));
  return r;
#endif
}
__device__ __forceinline__ float frcp(float x) {
#if __has_builtin(__builtin_amdgcn_rcpf)
  return __builtin_amdgcn_rcpf(x);
#else
  float r;
  asm("v_rcp_f32 %0, %1" : "=v"(r) : "v"(x));
  return r;
#endif
}
__device__ __forceinline__ void plswap(int a, int b, int h, int& x, int& y) {
#if __has_builtin(__builtin_amdgcn_permlane32_swap)
  (void)h;
  auto r = __builtin_amdgcn_permlane32_swap(a, b, false, false);
  x = r[0]; y = r[1];
#else
  const int ea = __shfl_xor(a, 32), eb = __shfl_xor(b, 32);
  x = h ? eb : a;
  y = h ? b : ea;
#endif
}

// ---------------------------------------------------------------------------
// Kernel 1: QKV GEMM (champion).  Grid (N/64, B, 3): z=0 q, 1 k, 2 v.
// k output in LDS-read chunk order [bh][n/32][half][n%32] (16B chunks).
// ---------------------------------------------------------------------------
__global__ __launch_bounds__(256) void qkv_mfma_kernel(
    const float* __restrict__ x, const float* __restrict__ w,
    const float* __restrict__ bias, unsigned short* __restrict__ qb,
    unsigned short* __restrict__ kb, unsigned short* __restrict__ vtb) {
  __shared__ char wl[64 * 128];   // W slice bf16, byte (2c)^((j&7)<<4)
  __shared__ char tl[4 * 2048];   // per-wave transpose buffers
  const int tid = threadIdx.x;
  const int lane = tid & 63, wid = tid >> 6;
  const int l31 = lane & 31, h = lane >> 5;
  const int nw = wid >> 1, jw = wid & 1;
  const int b = blockIdx.y, n0 = blockIdx.x * 64, z = blockIdx.z;

#pragma unroll
  for (int k = 0; k < 8; ++k) {   // stage W slice (64 rows x 64 c)
    const int p = tid + k * 256;
    const int j = p >> 5, c2 = (p & 31) * 2;
    const float2 wv = *(const float2*)(w + ((size_t)z * 64 + j) * 64 + c2);
    *(int*)(wl + j * 128 + ((2 * c2) ^ ((j & 7) << 4))) = cvtpk(wv.x, wv.y);
  }

  const int nA = n0 + nw * 32 + l31;
  bf16x8 af[4];
#pragma unroll
  for (int kk = 0; kk < 4; ++kk) {  // A-frags from global (coalesced over n)
    float e[8];
#pragma unroll
    for (int i = 0; i < 8; ++i)
      e[i] = x[((size_t)b * C + kk * 16 + h * 8 + i) * N + nA];
    i32x4 pk = {cvtpk(e[0], e[1]), cvtpk(e[2], e[3]),
                cvtpk(e[4], e[5]), cvtpk(e[6], e[7])};
    af[kk] = __builtin_bit_cast(bf16x8, pk);
  }
  __syncthreads();

  const int j = jw * 32 + l31;      // j within z-slice (0..63)
  f32x16 acc = {};
#pragma unroll
  for (int kk = 0; kk < 4; ++kk) {
    bf16x8 bf =
        *(const bf16x8*)(wl + j * 128 + ((kk * 32 + h * 16) ^ ((j & 7) << 4)));
    acc = __builtin_amdgcn_mfma_f32_32x32x16_bf16(af[kk], bf, acc, 0, 0, 0);
  }
  const float bj = bias[z * 64 + j];
  char* myt = tl + wid * 2048;

  if (z < 2) {  // q/k; LDS [32n][32j] bf16 (rows 64B)
    const float sc = (z == 0) ? QSCALE : 1.0f;
#pragma unroll
    for (int r = 0; r < 16; ++r) {
      const int n = (r & 3) + 8 * (r >> 2) + 4 * h;
      *(unsigned short*)(myt + n * 64 + l31 * 2) = f2bf((acc[r] + bj) * sc);
    }
#pragma unroll
    for (int u = 0; u < 2; ++u) {   // 128 chunks: (n, 8-j group)
      const int chunk = lane * 2 + u;
      const int n = chunk >> 2, c = chunk & 3;
      const uint4 vv = *(const uint4*)(myt + n * 64 + c * 16);
      const int jj = jw * 32 + c * 8;          // j-offset in 0..63
      const int hh = jj >> 4, half = (jj >> 3) & 1;
      const int bh = b * NH + hh;
      if (z == 0) {   // q: [bh][n][16]
        *(uint4*)(qb + ((size_t)bh * N + n0 + nw * 32 + n) * HD + half * 8) = vv;
      } else {        // k: chunk order [bh][tile32][half][r]
        const size_t ck = (size_t)bh * 8192 +
                          (size_t)((n0 >> 5) + nw) * 64 + half * 32 + n;
        *(uint4*)(kb + ck * 8) = vv;
      }
    }
  } else {      // v -> transposed [bh][d][N]; LDS [32j][32n] bf16
#pragma unroll
    for (int p = 0; p < 8; ++p) {
      const int r = 2 * p;
      const int n = (r & 3) + 8 * (r >> 2) + 4 * h;  // even
      *(int*)(myt + l31 * 64 + n * 2) = cvtpk(acc[r] + bj, acc[r + 1] + bj);
    }
#pragma unroll
    for (int u = 0; u < 2; ++u) {   // 128 chunks: (j, 8-n group)
      const int chunk = lane * 2 + u;
      const int jj = chunk >> 2, c = chunk & 3;
      const uint4 vv = *(const uint4*)(myt + jj * 64 + c * 16);
      const int vj = jw * 32 + jj;             // 0..63
      const int hh = vj >> 4, hd = vj & 15;
      *(uint4*)(vtb + ((size_t)(b * NH + hh) * HD + hd) * N + n0 + nw * 32 +
                c * 8) = vv;
    }
  }
}

// ---------------------------------------------------------------------------
// Kernel 2: attention (champion), software-pipelined.  Grid (N/128, MSA,
// B*NH) = 1024.  Conflict-free chunk-ordered K.
// ---------------------------------------------------------------------------
__global__ __launch_bounds__(256, 4) void attn_mfma_kernel(
    const unsigned short* __restrict__ qb, const unsigned short* __restrict__ kb,
    const unsigned short* __restrict__ vtb, unsigned short* __restrict__ part_o,
    float* __restrict__ part_l) {
  __shared__ uint4 ldsq[2 * BUFSZ / 16];
  char* ldsb = (char*)ldsq;
  const int tid  = threadIdx.x;
  const int lane = tid & 63;
  const int wid  = tid >> 6;
  const int l31  = lane & 31;
  const int h    = lane >> 5;
  const int bh = blockIdx.z;
  const int ms = blockIdx.y;
  const int q0 = blockIdx.x * 128 + wid * 32;
  const int m0 = ms * (N / MSA);
  constexpr int nt = (N / MSA) / MT;  // 4

  bf16x8 qf;
  {
    const uint4 qv =
        *(const uint4*)(qb + (((size_t)bh * N) + q0 + l31) * HD + h * 8);
    qf = __builtin_bit_cast(bf16x8, qv);
  }
  const unsigned short* kgp = kb + ((size_t)bh * 8192 + (m0 >> 5) * 64) * 8;
  const unsigned short* vgp = vtb + (size_t)bh * HD * N + m0;
  const int d0 = tid >> 5, c0 = tid & 31;
  const int d1 = d0 + 8;

  {
    uint4 k0 = *(const uint4*)(kgp + (size_t)tid * 8);
    uint4 k1 = *(const uint4*)(kgp + (size_t)(tid + 256) * 8);
    uint4 v0 = *(const uint4*)(vgp + (size_t)d0 * N + c0 * 8);
    uint4 v1 = *(const uint4*)(vgp + (size_t)d1 * N + c0 * 8);
    *(uint4*)(ldsb + tid * 16) = k0;
    *(uint4*)(ldsb + (tid + 256) * 16) = k1;
    *(uint4*)(ldsb + KSZ + d0 * VROW + c0 * 16) = v0;
    *(uint4*)(ldsb + KSZ + d1 * VROW + c0 * 16) = v1;
  }
  __syncthreads();

  // ones-column constant for lanes l31 >= 16 (l from PV accumulation)
  const int onef = (l31 == HD) ? 0x3F803F80 : 0;
  const i32x4 onev = {onef, onef, onef, onef};
  const bf16x8 vcst = __builtin_bit_cast(bf16x8, onev);

  f32x16 acc = {};
  int cur = 0;
  for (int t = 0; t < nt; ++t) {
    uint4 k0{}, k1{}, v0{}, v1{};
    const bool pre = (t + 1 < nt);
    if (pre) {
      const unsigned short* kt = kgp + (size_t)(t + 1) * 512 * 8;
      const unsigned short* vt = vgp + (t + 1) * MT;
      k0 = *(const uint4*)(kt + (size_t)tid * 8);
      k1 = *(const uint4*)(kt + (size_t)(tid + 256) * 8);
      v0 = *(const uint4*)(vt + (size_t)d0 * N + c0 * 8);
      v1 = *(const uint4*)(vt + (size_t)d1 * N + c0 * 8);
    }
    const char* kbase = ldsb + cur * BUFSZ;
    const char* vbase = kbase + KSZ;

    // pipeline prologue: K-frag 0 + its QK^T
    bf16x8 kf = *(const bf16x8*)(kbase + (h * 32 + l31) * 16);
    f32x16 zv = {};
    f32x16 stn = __builtin_amdgcn_mfma_f32_32x32x16_bf16(kf, qf, zv, 0, 0, 0);

#pragma unroll
    for (int cc = 0; cc < MT / 32; ++cc) {
      const f32x16 st = stn;
      if (cc + 1 < MT / 32) {   // issue next K read + QK^T before processing
        bf16x8 kf2 =
            *(const bf16x8*)(kbase + ((cc + 1) * 64 + h * 32 + l31) * 16);
        stn = __builtin_amdgcn_mfma_f32_32x32x16_bf16(kf2, qf, zv, 0, 0, 0);
      }
      // V fragments (independent of st) — issue early
      bf16x8 vf1, vf2;
      if (l31 < HD) {
        const char* vrow = vbase + l31 * VROW + cc * 64 + h * 16;
        vf1 = *(const bf16x8*)(vrow);
        vf2 = *(const bf16x8*)(vrow + 32);
      } else {
        vf1 = vcst;
        vf2 = vcst;
      }
      int dw[8];
#pragma unroll
      for (int jj = 0; jj < 8; ++jj)   // exp -> pack, pairwise (short lives)
        dw[jj] = cvtpk(fexp2(st[2 * jj]), fexp2(st[2 * jj + 1]));
      int w0, w1, w2, w3, w4, w5, w6, w7;
      plswap(dw[0], dw[2], h, w0, w2);
      plswap(dw[1], dw[3], h, w1, w3);
      plswap(dw[4], dw[6], h, w4, w6);
      plswap(dw[5], dw[7], h, w5, w7);
      const i32x4 a1 = {w0, w1, w2, w3};
      const i32x4 a2 = {w4, w5, w6, w7};
      acc = __builtin_amdgcn_mfma_f32_32x32x16_bf16(
          __builtin_bit_cast(bf16x8, a1), vf1, acc, 0, 0, 0);
      acc = __builtin_amdgcn_mfma_f32_32x32x16_bf16(
          __builtin_bit_cast(bf16x8, a2), vf2, acc, 0, 0, 0);
    }
    if (pre) {
      char* nb = ldsb + (cur ^ 1) * BUFSZ;
      *(uint4*)(nb + tid * 16) = k0;
      *(uint4*)(nb + (tid + 256) * 16) = k1;
      *(uint4*)(nb + KSZ + d0 * VROW + c0 * 16) = v0;
      *(uint4*)(nb + KSZ + d1 * VROW + c0 * 16) = v1;
    }
    __syncthreads();
    cur ^= 1;
  }

  const size_t pbase = ((size_t)bh * MSA + ms) * N + q0;
  if (l31 == HD) {
#pragma unroll
    for (int r = 0; r < 16; ++r)
      part_l[pbase + (r & 3) + 8 * (r >> 2) + 4 * h] = acc[r];
  }
  char* myt = ldsb + wid * 1024;
  if (l31 < HD) {
#pragma unroll
    for (int r = 0; r < 16; ++r) {
      const int q = (r & 3) + 8 * (r >> 2) + 4 * h;
      *(unsigned short*)(myt + q * 32 + l31 * 2) = f2bf(acc[r]);
    }
  }
  __syncthreads();
  const int qr = lane >> 1, half = lane & 1;
  const uint4 vv = *(const uint4*)(myt + qr * 32 + half * 16);
  *(uint4*)(part_o + (pbase + qr) * HD + half * 8) = vv;
}

// ---------------------------------------------------------------------------
// Kernel 3: fused combine + projection, k-split.  Grid (N/32, B), 256 thr /
// 4 waves = 2 c-tiles x 2 k-halves, 16KB LDS cross-wave reduce (r10 phase 3).
// ---------------------------------------------------------------------------
__global__ __launch_bounds__(256) void proj_mfma_kernel(
    const unsigned short* __restrict__ part_o, const float* __restrict__ part_l,
    const float* __restrict__ pw, const float* __restrict__ pb,
    float* __restrict__ out) {
  __shared__ char al[32 * 128];    // 4K  [32n][64d bf16] swizzled
  __shared__ char bl[64 * 128];    // 8K  [64c][64d bf16] swizzled
  __shared__ float red[4 * 1024];  // 16K [kw*2+cw][32c][32n] f32
  __shared__ float linv[128];      // [hh][n]
  const int tid = threadIdx.x;
  const int lane = tid & 63, wid = tid >> 6;
  const int l31 = lane & 31, h = lane >> 5;
  const int b = blockIdx.y, n0 = blockIdx.x * 32;

  if (tid < 128) {  // softmax denominators: 128 (hh, n) pairs
    const int hh = tid >> 5, n = tid & 31;
    const size_t base = ((size_t)(b * NH + hh) * MSA) * N + n0 + n;
    float l = 0.f;
#pragma unroll
    for (int ms = 0; ms < MSA; ++ms) l += part_l[base + (size_t)ms * N];
    linv[tid] = frcp(l);
  }
#pragma unroll
  for (int k = 0; k < 8; ++k) {   // stage W
    const int p = tid + k * 256;
    const int cR = p >> 5, d2 = (p & 31) * 2;
    const float2 wv = *(const float2*)(pw + cR * 64 + d2);
    *(int*)(bl + cR * 128 + ((2 * d2) ^ ((cR & 7) << 4))) = cvtpk(wv.x, wv.y);
  }
  __syncthreads();                 // linv ready

  {  // stage A: one (n, 8d-group) chunk per thread; combine 4 partials
    const int n = tid >> 3, d8 = tid & 7;
    const int hh = d8 >> 1, half = d8 & 1;
    const unsigned short* src =
        part_o + (((size_t)(b * NH + hh) * MSA) * N + n0 + n) * HD + half * 8;
    float s[8] = {0.f, 0.f, 0.f, 0.f, 0.f, 0.f, 0.f, 0.f};
#pragma unroll
    for (int ms = 0; ms < MSA; ++ms) {
      const uint4 v = *(const uint4*)(src + (size_t)ms * N * HD);
      const unsigned uu[4] = {v.x, v.y, v.z, v.w};
#pragma unroll
      for (int q = 0; q < 4; ++q) {
        s[2 * q]     += __uint_as_float(uu[q] << 16);
        s[2 * q + 1] += __uint_as_float(uu[q] & 0xffff0000u);
      }
    }
    const float iv = linv[hh * 32 + n];
    const i32x4 pk = {cvtpk(s[0] * iv, s[1] * iv), cvtpk(s[2] * iv, s[3] * iv),
                      cvtpk(s[4] * iv, s[5] * iv), cvtpk(s[6] * iv, s[7] * iv)};
    const int d = hh * 16 + half * 8;
    *(i32x4*)(al + n * 128 + ((2 * d) ^ ((n & 7) << 4))) = pk;
  }
  __syncthreads();

  const int kw = wid >> 1, cw = wid & 1;   // k-half x c-tile
  bf16x8 af2[2];
#pragma unroll
  for (int kk2 = 0; kk2 < 2; ++kk2) {
    const int kk = kw * 2 + kk2;
    af2[kk2] = *(const bf16x8*)(al + l31 * 128 +
                                ((kk * 32 + h * 16) ^ ((l31 & 7) << 4)));
  }
  const int c = cw * 32 + l31;
  f32x16 acc = {};
#pragma unroll
  for (int kk2 = 0; kk2 < 2; ++kk2) {
    const int kk = kw * 2 + kk2;
    bf16x8 bf = *(const bf16x8*)(bl + c * 128 +
                                 ((kk * 32 + h * 16) ^ ((c & 7) << 4)));
    acc = __builtin_amdgcn_mfma_f32_32x32x16_bf16(af2[kk2], bf, acc, 0, 0, 0);
  }
  float* myred = red + (kw * 2 + cw) * 1024;   // [32c][32n] f32
#pragma unroll
  for (int p = 0; p < 8; ++p) {
    const int r = 2 * p;
    const int nn = (r & 3) + 8 * (r >> 2) + 4 * h;   // even
    *(float2*)(myred + l31 * 32 + nn) = make_float2(acc[r], acc[r + 1]);
  }
  __syncthreads();
  if (kw == 0) {
    const float* r0 = red + cw * 1024;
    const float* r1 = red + (2 + cw) * 1024;
#pragma unroll
    for (int u = 0; u < 4; ++u) {
      const int chunk = lane * 4 + u;
      const int cc = chunk >> 3, cq = chunk & 7;
      const float4 va = *(const float4*)(r0 + cc * 32 + cq * 4);
      const float4 vb2 = *(const float4*)(r1 + cc * 32 + cq * 4);
      const float bc = pb[cw * 32 + cc];
      const float4 vo = {va.x + vb2.x + bc, va.y + vb2.y + bc,
                         va.z + vb2.z + bc, va.w + vb2.w + bc};
      *(float4*)(out + ((size_t)b * C + cw * 32 + cc) * N + n0 + cq * 4) = vo;
    }
  }
}

// ---------------------------------------------------------------------------
extern "C" void kernel_launch(void* const* d_in, const int* in_sizes, int n_in,
                              void* d_out, int out_size, void* d_ws, size_t ws_size,
                              hipStream_t stream) {
  const float* x      = (const float*)d_in[0];
  const float* qkv_w  = (const float*)d_in[1];
  const float* qkv_b  = (const float*)d_in[2];
  const float* proj_w = (const float*)d_in[3];
  const float* proj_b = (const float*)d_in[4];
  // d_in[5..8] (gate MLP) intentionally unused — see header note.
  unsigned short* qb     = (unsigned short*)d_ws;
  unsigned short* kb     = qb + KB_OFF;
  unsigned short* vtb    = qb + VT_OFF;
  unsigned short* part_o = qb + PO_OFF_U;
  float* part_l = (float*)d_ws + PL_OFF_F;
  float* out = (float*)d_out;

  qkv_mfma_kernel<<<dim3(N / 64, B, 3), 256, 0, stream>>>(
      x, qkv_w, qkv_b, qb, kb, vtb);
  attn_mfma_kernel<<<dim3(N / 128, MSA, B * NH), 256, 0, stream>>>(
      qb, kb, vtb, part_o, part_l);
  proj_mfma_kernel<<<dim3(N / 32, B), 256, 0, stream>>>(
      part_o, part_l, proj_w, proj_b, out);
}

// Round 24
// 34.803 us; speedup vs baseline: 1.0457x; 1.0010x over previous
//
#include <hip/hip_runtime.h>
#include <cstdint>

// EdgeGateAttention, MI355X — FINAL (round 23 config, best measured 34.84us;
// champion band 34.84-35.15 across 4 runs).  Session: 181 -> 34.8us (5.2x).
//   qkv MFMA GEMM (384 blk, chunk-ordered K/V epilogues)
//   -> attn MFMA (1024 blk, MSA=4, conflict-free K, SW-pipelined, bf16 partials)
//   -> fused combine+proj (512 blk, k-split 4-wave).
// Falsified: trans-bound, launch-overhead, occupancy push, 2-tile ILP,
// LDS-free operands, port-balancing, proj k-split (neutral, kept: best run).
// Material wins: MFMA everywhere, partial-free layouts, bank-conflict fix.
//
// Gate skip (validated r1): gate renorm makes it identity to O(1e-8).
// Softmax: raw v_exp_f32, no max subtraction; 0.25*log2(e) folded into Q.
// l from ones-column (d=16) of the PV MFMA.

namespace {
constexpr int B  = 2;
constexpr int C  = 64;
constexpr int NH = 4;
constexpr int HD = 16;
constexpr int N  = 4096;
constexpr int MSA = 4;              // attention m-split
constexpr int MT  = 256;            // K/V m-tile rows staged in LDS
constexpr int VROW  = 2 * MT + 16;  // 528 B
constexpr int KSZ   = MT * 32;      // 8192 B
constexpr int BUFSZ = KSZ + HD * VROW;  // 16640 B

constexpr size_t QKV1     = (size_t)B * NH * N * HD;        // 524288
constexpr size_t KB_OFF   = QKV1;
constexpr size_t VT_OFF   = 2 * QKV1;
constexpr size_t PO_OFF_U = 3 * QKV1;                       // ushort idx
constexpr size_t PO_SZ    = (size_t)B * NH * MSA * N * HD;  // 2097152 ushorts
constexpr size_t PL_OFF_F = (PO_OFF_U + PO_SZ) / 2;         // float idx
constexpr float QSCALE = 0.36067376022224085f;              // 0.25 * log2(e)
}

typedef short bf16x8 __attribute__((ext_vector_type(8)));
typedef float f32x16 __attribute__((ext_vector_type(16)));
typedef int   i32x4  __attribute__((ext_vector_type(4)));

__device__ __forceinline__ unsigned short f2bf(float f) {  // RNE f32->bf16
  unsigned u = __float_as_uint(f);
  u = (u + 0x7fffu + ((u >> 16) & 1u)) >> 16;
  return (unsigned short)u;
}
__device__ __forceinline__ int cvtpk(float lo, float hi) {
  int r;
  asm("v_cvt_pk_bf16_f32 %0, %1, %2" : "=v"(r) : "v"(lo), "v"(hi));
  return r;
}
__device__ __forceinline__ float fexp2(float x) {  // raw v_exp_f32
#if __has_builtin(__builtin_amdgcn_exp2f)
  return __builtin_amdgcn_exp2f(x);
#else
  float r;
  asm("v_exp_f32 %0, %1" : "=v"(r) : "v"(x));
  return r;
#endif
}
__device__ __forceinline__ float frcp(float x) {
#if __has_builtin(__builtin_amdgcn_rcpf)
  return __builtin_amdgcn_rcpf(x);
#else
  float r;
  asm("v_rcp_f32 %0, %1" : "=v"(r) : "v"(x));
  return r;
#endif
}
__device__ __forceinline__ void plswap(int a, int b, int h, int& x, int& y) {
#if __has_builtin(__builtin_amdgcn_permlane32_swap)
  (void)h;
  auto r = __builtin_amdgcn_permlane32_swap(a, b, false, false);
  x = r[0]; y = r[1];
#else
  const int ea = __shfl_xor(a, 32), eb = __shfl_xor(b, 32);
  x = h ? eb : a;
  y = h ? b : ea;
#endif
}

// ---------------------------------------------------------------------------
// Kernel 1: QKV GEMM.  Grid (N/64, B, 3): z=0 q, 1 k, 2 v.
// k output in LDS-read chunk order [bh][n/32][half][n%32] (16B chunks).
// ---------------------------------------------------------------------------
__global__ __launch_bounds__(256) void qkv_mfma_kernel(
    const float* __restrict__ x, const float* __restrict__ w,
    const float* __restrict__ bias, unsigned short* __restrict__ qb,
    unsigned short* __restrict__ kb, unsigned short* __restrict__ vtb) {
  __shared__ char wl[64 * 128];   // W slice bf16, byte (2c)^((j&7)<<4)
  __shared__ char tl[4 * 2048];   // per-wave transpose buffers
  const int tid = threadIdx.x;
  const int lane = tid & 63, wid = tid >> 6;
  const int l31 = lane & 31, h = lane >> 5;
  const int nw = wid >> 1, jw = wid & 1;
  const int b = blockIdx.y, n0 = blockIdx.x * 64, z = blockIdx.z;

#pragma unroll
  for (int k = 0; k < 8; ++k) {   // stage W slice (64 rows x 64 c)
    const int p = tid + k * 256;
    const int j = p >> 5, c2 = (p & 31) * 2;
    const float2 wv = *(const float2*)(w + ((size_t)z * 64 + j) * 64 + c2);
    *(int*)(wl + j * 128 + ((2 * c2) ^ ((j & 7) << 4))) = cvtpk(wv.x, wv.y);
  }

  const int nA = n0 + nw * 32 + l31;
  bf16x8 af[4];
#pragma unroll
  for (int kk = 0; kk < 4; ++kk) {  // A-frags from global (coalesced over n)
    float e[8];
#pragma unroll
    for (int i = 0; i < 8; ++i)
      e[i] = x[((size_t)b * C + kk * 16 + h * 8 + i) * N + nA];
    i32x4 pk = {cvtpk(e[0], e[1]), cvtpk(e[2], e[3]),
                cvtpk(e[4], e[5]), cvtpk(e[6], e[7])};
    af[kk] = __builtin_bit_cast(bf16x8, pk);
  }
  __syncthreads();

  const int j = jw * 32 + l31;      // j within z-slice (0..63)
  f32x16 acc = {};
#pragma unroll
  for (int kk = 0; kk < 4; ++kk) {
    bf16x8 bf =
        *(const bf16x8*)(wl + j * 128 + ((kk * 32 + h * 16) ^ ((j & 7) << 4)));
    acc = __builtin_amdgcn_mfma_f32_32x32x16_bf16(af[kk], bf, acc, 0, 0, 0);
  }
  const float bj = bias[z * 64 + j];
  char* myt = tl + wid * 2048;

  if (z < 2) {  // q/k; LDS [32n][32j] bf16 (rows 64B)
    const float sc = (z == 0) ? QSCALE : 1.0f;
#pragma unroll
    for (int r = 0; r < 16; ++r) {
      const int n = (r & 3) + 8 * (r >> 2) + 4 * h;
      *(unsigned short*)(myt + n * 64 + l31 * 2) = f2bf((acc[r] + bj) * sc);
    }
#pragma unroll
    for (int u = 0; u < 2; ++u) {   // 128 chunks: (n, 8-j group)
      const int chunk = lane * 2 + u;
      const int n = chunk >> 2, c = chunk & 3;
      const uint4 vv = *(const uint4*)(myt + n * 64 + c * 16);
      const int jj = jw * 32 + c * 8;          // j-offset in 0..63
      const int hh = jj >> 4, half = (jj >> 3) & 1;
      const int bh = b * NH + hh;
      if (z == 0) {   // q: [bh][n][16]
        *(uint4*)(qb + ((size_t)bh * N + n0 + nw * 32 + n) * HD + half * 8) = vv;
      } else {        // k: chunk order [bh][tile32][half][r]
        const size_t ck = (size_t)bh * 8192 +
                          (size_t)((n0 >> 5) + nw) * 64 + half * 32 + n;
        *(uint4*)(kb + ck * 8) = vv;
      }
    }
  } else {      // v -> transposed [bh][d][N]; LDS [32j][32n] bf16
#pragma unroll
    for (int p = 0; p < 8; ++p) {
      const int r = 2 * p;
      const int n = (r & 3) + 8 * (r >> 2) + 4 * h;  // even
      *(int*)(myt + l31 * 64 + n * 2) = cvtpk(acc[r] + bj, acc[r + 1] + bj);
    }
#pragma unroll
    for (int u = 0; u < 2; ++u) {   // 128 chunks: (j, 8-n group)
      const int chunk = lane * 2 + u;
      const int jj = chunk >> 2, c = chunk & 3;
      const uint4 vv = *(const uint4*)(myt + jj * 64 + c * 16);
      const int vj = jw * 32 + jj;             // 0..63
      const int hh = vj >> 4, hd = vj & 15;
      *(uint4*)(vtb + ((size_t)(b * NH + hh) * HD + hd) * N + n0 + nw * 32 +
                c * 8) = vv;
    }
  }
}

// ---------------------------------------------------------------------------
// Kernel 2: attention, software-pipelined.  Grid (N/128, MSA, B*NH) = 1024.
// Conflict-free K path (chunk-ordered kb).
// ---------------------------------------------------------------------------
__global__ __launch_bounds__(256, 4) void attn_mfma_kernel(
    const unsigned short* __restrict__ qb, const unsigned short* __restrict__ kb,
    const unsigned short* __restrict__ vtb, unsigned short* __restrict__ part_o,
    float* __restrict__ part_l) {
  __shared__ uint4 ldsq[2 * BUFSZ / 16];
  char* ldsb = (char*)ldsq;
  const int tid  = threadIdx.x;
  const int lane = tid & 63;
  const int wid  = tid >> 6;
  const int l31  = lane & 31;
  const int h    = lane >> 5;
  const int bh = blockIdx.z;
  const int ms = blockIdx.y;
  const int q0 = blockIdx.x * 128 + wid * 32;
  const int m0 = ms * (N / MSA);
  constexpr int nt = (N / MSA) / MT;  // 4

  bf16x8 qf;
  {
    const uint4 qv =
        *(const uint4*)(qb + (((size_t)bh * N) + q0 + l31) * HD + h * 8);
    qf = __builtin_bit_cast(bf16x8, qv);
  }
  const unsigned short* kgp = kb + ((size_t)bh * 8192 + (m0 >> 5) * 64) * 8;
  const unsigned short* vgp = vtb + (size_t)bh * HD * N + m0;
  const int d0 = tid >> 5, c0 = tid & 31;
  const int d1 = d0 + 8;

  {
    uint4 k0 = *(const uint4*)(kgp + (size_t)tid * 8);
    uint4 k1 = *(const uint4*)(kgp + (size_t)(tid + 256) * 8);
    uint4 v0 = *(const uint4*)(vgp + (size_t)d0 * N + c0 * 8);
    uint4 v1 = *(const uint4*)(vgp + (size_t)d1 * N + c0 * 8);
    *(uint4*)(ldsb + tid * 16) = k0;
    *(uint4*)(ldsb + (tid + 256) * 16) = k1;
    *(uint4*)(ldsb + KSZ + d0 * VROW + c0 * 16) = v0;
    *(uint4*)(ldsb + KSZ + d1 * VROW + c0 * 16) = v1;
  }
  __syncthreads();

  // ones-column constant for lanes l31 >= 16 (l from PV accumulation)
  const int onef = (l31 == HD) ? 0x3F803F80 : 0;
  const i32x4 onev = {onef, onef, onef, onef};
  const bf16x8 vcst = __builtin_bit_cast(bf16x8, onev);

  f32x16 acc = {};
  int cur = 0;
  for (int t = 0; t < nt; ++t) {
    uint4 k0{}, k1{}, v0{}, v1{};
    const bool pre = (t + 1 < nt);
    if (pre) {
      const unsigned short* kt = kgp + (size_t)(t + 1) * 512 * 8;
      const unsigned short* vt = vgp + (t + 1) * MT;
      k0 = *(const uint4*)(kt + (size_t)tid * 8);
      k1 = *(const uint4*)(kt + (size_t)(tid + 256) * 8);
      v0 = *(const uint4*)(vt + (size_t)d0 * N + c0 * 8);
      v1 = *(const uint4*)(vt + (size_t)d1 * N + c0 * 8);
    }
    const char* kbase = ldsb + cur * BUFSZ;
    const char* vbase = kbase + KSZ;

    // pipeline prologue: K-frag 0 + its QK^T
    bf16x8 kf = *(const bf16x8*)(kbase + (h * 32 + l31) * 16);
    f32x16 zv = {};
    f32x16 stn = __builtin_amdgcn_mfma_f32_32x32x16_bf16(kf, qf, zv, 0, 0, 0);

#pragma unroll
    for (int cc = 0; cc < MT / 32; ++cc) {
      const f32x16 st = stn;
      if (cc + 1 < MT / 32) {   // issue next K read + QK^T before processing
        bf16x8 kf2 =
            *(const bf16x8*)(kbase + ((cc + 1) * 64 + h * 32 + l31) * 16);
        stn = __builtin_amdgcn_mfma_f32_32x32x16_bf16(kf2, qf, zv, 0, 0, 0);
      }
      // V fragments (independent of st) — issue early
      bf16x8 vf1, vf2;
      if (l31 < HD) {
        const char* vrow = vbase + l31 * VROW + cc * 64 + h * 16;
        vf1 = *(const bf16x8*)(vrow);
        vf2 = *(const bf16x8*)(vrow + 32);
      } else {
        vf1 = vcst;
        vf2 = vcst;
      }
      int dw[8];
#pragma unroll
      for (int jj = 0; jj < 8; ++jj)   // exp -> pack, pairwise (short lives)
        dw[jj] = cvtpk(fexp2(st[2 * jj]), fexp2(st[2 * jj + 1]));
      int w0, w1, w2, w3, w4, w5, w6, w7;
      plswap(dw[0], dw[2], h, w0, w2);
      plswap(dw[1], dw[3], h, w1, w3);
      plswap(dw[4], dw[6], h, w4, w6);
      plswap(dw[5], dw[7], h, w5, w7);
      const i32x4 a1 = {w0, w1, w2, w3};
      const i32x4 a2 = {w4, w5, w6, w7};
      acc = __builtin_amdgcn_mfma_f32_32x32x16_bf16(
          __builtin_bit_cast(bf16x8, a1), vf1, acc, 0, 0, 0);
      acc = __builtin_amdgcn_mfma_f32_32x32x16_bf16(
          __builtin_bit_cast(bf16x8, a2), vf2, acc, 0, 0, 0);
    }
    if (pre) {
      char* nb = ldsb + (cur ^ 1) * BUFSZ;
      *(uint4*)(nb + tid * 16) = k0;
      *(uint4*)(nb + (tid + 256) * 16) = k1;
      *(uint4*)(nb + KSZ + d0 * VROW + c0 * 16) = v0;
      *(uint4*)(nb + KSZ + d1 * VROW + c0 * 16) = v1;
    }
    __syncthreads();
    cur ^= 1;
  }

  const size_t pbase = ((size_t)bh * MSA + ms) * N + q0;
  if (l31 == HD) {
#pragma unroll
    for (int r = 0; r < 16; ++r)
      part_l[pbase + (r & 3) + 8 * (r >> 2) + 4 * h] = acc[r];
  }
  char* myt = ldsb + wid * 1024;
  if (l31 < HD) {
#pragma unroll
    for (int r = 0; r < 16; ++r) {
      const int q = (r & 3) + 8 * (r >> 2) + 4 * h;
      *(unsigned short*)(myt + q * 32 + l31 * 2) = f2bf(acc[r]);
    }
  }
  __syncthreads();
  const int qr = lane >> 1, half = lane & 1;
  const uint4 vv = *(const uint4*)(myt + qr * 32 + half * 16);
  *(uint4*)(part_o + (pbase + qr) * HD + half * 8) = vv;
}

// ---------------------------------------------------------------------------
// Kernel 3: fused combine + projection, k-split.  Grid (N/32, B), 256 thr /
// 4 waves = 2 c-tiles x 2 k-halves, 16KB LDS cross-wave reduce.
// ---------------------------------------------------------------------------
__global__ __launch_bounds__(256) void proj_mfma_kernel(
    const unsigned short* __restrict__ part_o, const float* __restrict__ part_l,
    const float* __restrict__ pw, const float* __restrict__ pb,
    float* __restrict__ out) {
  __shared__ char al[32 * 128];    // 4K  [32n][64d bf16] swizzled
  __shared__ char bl[64 * 128];    // 8K  [64c][64d bf16] swizzled
  __shared__ float red[4 * 1024];  // 16K [kw*2+cw][32c][32n] f32
  __shared__ float linv[128];      // [hh][n]
  const int tid = threadIdx.x;
  const int lane = tid & 63, wid = tid >> 6;
  const int l31 = lane & 31, h = lane >> 5;
  const int b = blockIdx.y, n0 = blockIdx.x * 32;

  if (tid < 128) {  // softmax denominators: 128 (hh, n) pairs
    const int hh = tid >> 5, n = tid & 31;
    const size_t base = ((size_t)(b * NH + hh) * MSA) * N + n0 + n;
    float l = 0.f;
#pragma unroll
    for (int ms = 0; ms < MSA; ++ms) l += part_l[base + (size_t)ms * N];
    linv[tid] = frcp(l);
  }
#pragma unroll
  for (int k = 0; k < 8; ++k) {   // stage W
    const int p = tid + k * 256;
    const int cR = p >> 5, d2 = (p & 31) * 2;
    const float2 wv = *(const float2*)(pw + cR * 64 + d2);
    *(int*)(bl + cR * 128 + ((2 * d2) ^ ((cR & 7) << 4))) = cvtpk(wv.x, wv.y);
  }
  __syncthreads();                 // linv ready

  {  // stage A: one (n, 8d-group) chunk per thread; combine 4 partials
    const int n = tid >> 3, d8 = tid & 7;
    const int hh = d8 >> 1, half = d8 & 1;
    const unsigned short* src =
        part_o + (((size_t)(b * NH + hh) * MSA) * N + n0 + n) * HD + half * 8;
    float s[8] = {0.f, 0.f, 0.f, 0.f, 0.f, 0.f, 0.f, 0.f};
#pragma unroll
    for (int ms = 0; ms < MSA; ++ms) {
      const uint4 v = *(const uint4*)(src + (size_t)ms * N * HD);
      const unsigned uu[4] = {v.x, v.y, v.z, v.w};
#pragma unroll
      for (int q = 0; q < 4; ++q) {
        s[2 * q]     += __uint_as_float(uu[q] << 16);
        s[2 * q + 1] += __uint_as_float(uu[q] & 0xffff0000u);
      }
    }
    const float iv = linv[hh * 32 + n];
    const i32x4 pk = {cvtpk(s[0] * iv, s[1] * iv), cvtpk(s[2] * iv, s[3] * iv),
                      cvtpk(s[4] * iv, s[5] * iv), cvtpk(s[6] * iv, s[7] * iv)};
    const int d = hh * 16 + half * 8;
    *(i32x4*)(al + n * 128 + ((2 * d) ^ ((n & 7) << 4))) = pk;
  }
  __syncthreads();

  const int kw = wid >> 1, cw = wid & 1;   // k-half x c-tile
  bf16x8 af2[2];
#pragma unroll
  for (int kk2 = 0; kk2 < 2; ++kk2) {
    const int kk = kw * 2 + kk2;
    af2[kk2] = *(const bf16x8*)(al + l31 * 128 +
                                ((kk * 32 + h * 16) ^ ((l31 & 7) << 4)));
  }
  const int c = cw * 32 + l31;
  f32x16 acc = {};
#pragma unroll
  for (int kk2 = 0; kk2 < 2; ++kk2) {
    const int kk = kw * 2 + kk2;
    bf16x8 bf = *(const bf16x8*)(bl + c * 128 +
                                 ((kk * 32 + h * 16) ^ ((c & 7) << 4)));
    acc = __builtin_amdgcn_mfma_f32_32x32x16_bf16(af2[kk2], bf, acc, 0, 0, 0);
  }
  float* myred = red + (kw * 2 + cw) * 1024;   // [32c][32n] f32
#pragma unroll
  for (int p = 0; p < 8; ++p) {
    const int r = 2 * p;
    const int nn = (r & 3) + 8 * (r >> 2) + 4 * h;   // even
    *(float2*)(myred + l31 * 32 + nn) = make_float2(acc[r], acc[r + 1]);
  }
  __syncthreads();
  if (kw == 0) {
    const float* r0 = red + cw * 1024;
    const float* r1 = red + (2 + cw) * 1024;
#pragma unroll
    for (int u = 0; u < 4; ++u) {
      const int chunk = lane * 4 + u;
      const int cc = chunk >> 3, cq = chunk & 7;
      const float4 va = *(const float4*)(r0 + cc * 32 + cq * 4);
      const float4 vb2 = *(const float4*)(r1 + cc * 32 + cq * 4);
      const float bc = pb[cw * 32 + cc];
      const float4 vo = {va.x + vb2.x + bc, va.y + vb2.y + bc,
                         va.z + vb2.z + bc, va.w + vb2.w + bc};
      *(float4*)(out + ((size_t)b * C + cw * 32 + cc) * N + n0 + cq * 4) = vo;
    }
  }
}

// ---------------------------------------------------------------------------
extern "C" void kernel_launch(void* const* d_in, const int* in_sizes, int n_in,
                              void* d_out, int out_size, void* d_ws, size_t ws_size,
                              hipStream_t stream) {
  const float* x      = (const float*)d_in[0];
  const float* qkv_w  = (const float*)d_in[1];
  const float* qkv_b  = (const float*)d_in[2];
  const float* proj_w = (const float*)d_in[3];
  const float* proj_b = (const float*)d_in[4];
  // d_in[5..8] (gate MLP) intentionally unused — see header note.
  unsigned short* qb     = (unsigned short*)d_ws;
  unsigned short* kb     = qb + KB_OFF;
  unsigned short* vtb    = qb + VT_OFF;
  unsigned short* part_o = qb + PO_OFF_U;
  float* part_l = (float*)d_ws + PL_OFF_F;
  float* out = (float*)d_out;

  qkv_mfma_kernel<<<dim3(N / 64, B, 3), 256, 0, stream>>>(
      x, qkv_w, qkv_b, qb, kb, vtb);
  attn_mfma_kernel<<<dim3(N / 128, MSA, B * NH), 256, 0, stream>>>(
      qb, kb, vtb, part_o, part_l);
  proj_mfma_kernel<<<dim3(N / 32, B), 256, 0, stream>>>(
      part_o, part_l, proj_w, proj_b, out);
}